// Round 4
// baseline (587.880 us; speedup 1.0000x reference)
//
#include <hip/hip_runtime.h>
#include <math.h>

typedef __attribute__((ext_vector_type(4))) float f32x4;
typedef _Float16 f16;
typedef __attribute__((ext_vector_type(8))) _Float16 f16x8;

// Problem constants (DeepSeek-V3 gate: hidden (4,2048,7168), 256 experts)
constexpr int H       = 7168;
constexpr int E       = 256;
constexpr int T_TOTAL = 8192;     // 4*2048 tokens

constexpr int KSPLIT  = 4;
constexpr int K_SLICE = H / KSPLIT;    // 1792
constexpr int BK      = 64;            // K-chunk per LDS stage (2 MFMA K-steps)
constexpr int NCH     = K_SLICE / BK;  // 28 chunks per block
constexpr int MT      = 128;           // tokens per GEMM block (8 mtiles)

constexpr int N_GROUP    = 8;
constexpr int GROUP_SZ   = E / N_GROUP;   // 32
constexpr int TOPK_GROUP = 4;
constexpr int TOP_K      = 8;
constexpr int SCS        = 261;           // score row stride (coprime 32)

constexpr size_t SCORES_OFF = 8u * 1024 * 1024;   // ws: wf at 0 (7.34MB), scores at 8MB

// ---------------------------------------------------------------------------
// Kernel 1: split w (fp32) into f16 hi/lo in MFMA B-fragment order:
//   wf[((kc*16 + ntile)*2 + s)*512 + lane*8 + j]
//   kc = h>>5, ntile = e>>4, s = 0(hi)/1(lo), lane = ((h>>3)&3)<<4 | (e&15)
// ---------------------------------------------------------------------------
__global__ __launch_bounds__(64) void pack_w_kernel(const float* __restrict__ w,
                                                    f16* __restrict__ wf)
{
    const int l  = threadIdx.x;
    const int nt = blockIdx.x & 15;
    const int kc = blockIdx.x >> 4;
    const int e  = nt * 16 + (l & 15);
    const int h  = kc * 32 + (l >> 4) * 8;
    const float* src = &w[(size_t)e * H + h];
    f32x4 v0 = *reinterpret_cast<const f32x4*>(src);
    f32x4 v1 = *reinterpret_cast<const f32x4*>(src + 4);
    float v[8] = {v0[0], v0[1], v0[2], v0[3], v1[0], v1[1], v1[2], v1[3]};
    f16x8 hi, lo;
    #pragma unroll
    for (int j = 0; j < 8; ++j) {
        f16 h16 = (f16)v[j];
        hi[j] = h16;
        lo[j] = (f16)(v[j] - (float)h16);
    }
    const size_t base = (((size_t)kc * 16 + nt) * 2) * 512 + (size_t)l * 8;
    *reinterpret_cast<f16x8*>(&wf[base])       = hi;
    *reinterpret_cast<f16x8*>(&wf[base + 512]) = lo;
}

// ---------------------------------------------------------------------------
// Kernel 2: router GEMM, f16-split MFMA (acc += Ahi*Bhi + Ahi*Blo + Alo*Bhi).
// Grid: 256 = 64 M-tiles x 4 K-slices -> exactly 1 block/CU; kslice = bid&3 so
// each XCD (bid%8 round-robin) touches ONE 1.84MB wf slice (L2-resident).
// Block: 512 thr = 8 waves. Block tile 128m x 256n; wave tile 32m x 128n
// (2 mtiles x 8 ntiles) -> 16 B-frag loads feed 48 MFMAs per K-step.
// A is staged hi/lo in LDS in MFMA *fragment order* (lane*16B -> conflict-free).
// ---------------------------------------------------------------------------
__global__ __launch_bounds__(512, 2) void gemm_kernel(
    const float* __restrict__ x,      // [T_TOTAL, H] fp32
    const f16*   __restrict__ wf,     // packed B-fragments
    float* __restrict__ scores)       // [T_TOTAL][KSPLIT][E] partial logits
{
    // [buf][mtile 0..7][ks 0..1][s 0..1][lane 0..63][j 0..7] f16
    __shared__ __align__(16) f16 x_lds[2][8 * 2 * 2 * 512];   // 2 x 32 KB

    const int tid  = threadIdx.x;
    const int lane = tid & 63;
    const int wave = tid >> 6;     // 0..7
    const int wm   = wave >> 1;    // 0..3: m offset wm*32
    const int wn   = wave & 1;     // 0..1: experts wn*128..+127
    const int lm   = lane & 15;
    const int kq   = lane >> 4;

    const int bid = blockIdx.x;
    const int ksl = bid & 3;
    const int mb  = bid >> 2;      // 0..63
    const int t0  = mb * MT;
    const int k0  = ksl * K_SLICE;

    // loader mapping: wave = mtile (0..7), lane: row = lm, col-quad = kq.
    // per chunk each thread loads 16 floats: cols kq*8..+7 for ks=0 and ks=1.
    const float* xrow = &x[(size_t)(t0 + wave * 16 + lm) * H + k0 + kq * 8];

    f32x4 acc[2][8];
    #pragma unroll
    for (int mt = 0; mt < 2; ++mt)
        #pragma unroll
        for (int nt = 0; nt < 8; ++nt)
            acc[mt][nt] = (f32x4){0.f, 0.f, 0.f, 0.f};

    // split 8 floats -> hi/lo f16x8 and write one fragment slot (lane*16B)
    auto stage = [&](int buf, int ks, f32x4 v0, f32x4 v1) {
        float v[8] = {v0[0], v0[1], v0[2], v0[3], v1[0], v1[1], v1[2], v1[3]};
        f16x8 hi, lo;
        #pragma unroll
        for (int j = 0; j < 8; ++j) {
            f16 h16 = (f16)v[j];
            hi[j] = h16;
            lo[j] = (f16)(v[j] - (float)h16);
        }
        f16* base = &x_lds[buf][((wave * 2 + ks) * 2) * 512 + lane * 8];
        *reinterpret_cast<f16x8*>(base)       = hi;   // s=0
        *reinterpret_cast<f16x8*>(base + 512) = lo;   // s=1
    };

    // prologue: stage chunk 0 into buf 0
    {
        f32x4 a0 = *reinterpret_cast<const f32x4*>(xrow);
        f32x4 a1 = *reinterpret_cast<const f32x4*>(xrow + 4);
        f32x4 b0 = *reinterpret_cast<const f32x4*>(xrow + 32);
        f32x4 b1 = *reinterpret_cast<const f32x4*>(xrow + 36);
        stage(0, 0, a0, a1);
        stage(0, 1, b0, b1);
    }
    __syncthreads();

    for (int ch = 0; ch < NCH; ++ch) {
        const int buf = ch & 1;
        // prefetch next chunk's x into registers (latency hidden by MFMAs)
        f32x4 n00, n01, n10, n11;
        if (ch + 1 < NCH) {
            const float* nx = xrow + (ch + 1) * 64;
            n00 = *reinterpret_cast<const f32x4*>(nx);
            n01 = *reinterpret_cast<const f32x4*>(nx + 4);
            n10 = *reinterpret_cast<const f32x4*>(nx + 32);
            n11 = *reinterpret_cast<const f32x4*>(nx + 36);
        }
        #pragma unroll
        for (int ks = 0; ks < 2; ++ks) {
            const int kc = (k0 >> 5) + ch * 2 + ks;
            // all 16 B fragments batched (independent -> deep vmcnt pipeline)
            f16x8 b[8][2];
            #pragma unroll
            for (int nt = 0; nt < 8; ++nt)
                #pragma unroll
                for (int s = 0; s < 2; ++s)
                    b[nt][s] = *reinterpret_cast<const f16x8*>(
                        &wf[(((size_t)kc * 16 + wn * 8 + nt) * 2 + s) * 512 + lane * 8]);
            // A fragments: fragment-order LDS, lane*16B -> conflict-free
            f16x8 a[2][2];
            #pragma unroll
            for (int mt = 0; mt < 2; ++mt)
                #pragma unroll
                for (int s = 0; s < 2; ++s)
                    a[mt][s] = *reinterpret_cast<const f16x8*>(
                        &x_lds[buf][(((wm * 2 + mt) * 2 + ks) * 2 + s) * 512 + lane * 8]);
            #pragma unroll
            for (int mt = 0; mt < 2; ++mt)
                #pragma unroll
                for (int nt = 0; nt < 8; ++nt)
                    acc[mt][nt] = __builtin_amdgcn_mfma_f32_16x16x32_f16(
                        a[mt][0], b[nt][0], acc[mt][nt], 0, 0, 0);
            #pragma unroll
            for (int mt = 0; mt < 2; ++mt)
                #pragma unroll
                for (int nt = 0; nt < 8; ++nt)
                    acc[mt][nt] = __builtin_amdgcn_mfma_f32_16x16x32_f16(
                        a[mt][0], b[nt][1], acc[mt][nt], 0, 0, 0);
            #pragma unroll
            for (int mt = 0; mt < 2; ++mt)
                #pragma unroll
                for (int nt = 0; nt < 8; ++nt)
                    acc[mt][nt] = __builtin_amdgcn_mfma_f32_16x16x32_f16(
                        a[mt][1], b[nt][0], acc[mt][nt], 0, 0, 0);
        }
        if (ch + 1 < NCH) {
            stage(buf ^ 1, 0, n00, n01);
            stage(buf ^ 1, 1, n10, n11);
        }
        __syncthreads();
    }

    // epilogue: raw partial logits, layout [T][KSPLIT][E]
    // C/D: col(expert)=lane&15, row(token)=(lane>>4)*4+reg
    #pragma unroll
    for (int mt = 0; mt < 2; ++mt)
        #pragma unroll
        for (int nt = 0; nt < 8; ++nt)
            #pragma unroll
            for (int r = 0; r < 4; ++r) {
                const int tok = wm * 32 + mt * 16 + kq * 4 + r;
                const int e   = wn * 128 + nt * 16 + lm;
                scores[(((size_t)(t0 + tok)) * KSPLIT + ksl) * E + e] = acc[mt][nt][r];
            }
}

// ---------------------------------------------------------------------------
// Kernel 3: reduce K-split partials, sigmoid, grouped top-k gating.
// 512 blocks x 256 threads; 16 tokens/block; per-token partials contiguous
// (4KB) so the unrolled independent iterations pipeline their loads.
// ---------------------------------------------------------------------------
__global__ __launch_bounds__(256) void gate_kernel(
    const float* __restrict__ scores,  // [T_TOTAL][KSPLIT][E]
    const float* __restrict__ bias,    // [E]
    float* __restrict__ out)           // [T*8 idx floats][T*8 weight floats]
{
    __shared__ float sc_lds[16 * SCS];
    __shared__ float bias_lds[E];
    const int tid = threadIdx.x;
    const int t0  = blockIdx.x * 16;

    bias_lds[tid] = bias[tid];

    #pragma unroll 4
    for (int t = 0; t < 16; ++t) {
        const float* p = &scores[((size_t)(t0 + t) * KSPLIT) * E + tid];
        float s = 0.f;
        #pragma unroll
        for (int k = 0; k < KSPLIT; ++k) s += p[k * E];
        sc_lds[t * SCS + tid] = 1.0f / (1.0f + expf(-s));
    }
    __syncthreads();

    if (tid < 16) {
        const float* sc = &sc_lds[tid * SCS];
        float gs[N_GROUP];
        #pragma unroll
        for (int g = 0; g < N_GROUP; ++g) {
            const int base = g * GROUP_SZ;
            float m1 = -INFINITY, m2 = -INFINITY;
            for (int i = 0; i < GROUP_SZ; ++i) {
                const float v = sc[base + i] + bias_lds[base + i];
                if (v > m1) { m2 = m1; m1 = v; }
                else if (v > m2) { m2 = v; }
            }
            gs[g] = m1 + m2;
        }
        bool gsel[N_GROUP] = {false, false, false, false, false, false, false, false};
        for (int r = 0; r < TOPK_GROUP; ++r) {
            float best = -INFINITY; int bi = 0;
            for (int g = 0; g < N_GROUP; ++g)
                if (!gsel[g] && gs[g] > best) { best = gs[g]; bi = g; }
            gsel[bi] = true;
        }
        int ag[TOPK_GROUP]; int na = 0;
        for (int g = 0; g < N_GROUP; ++g) if (gsel[g]) ag[na++] = g;
        unsigned long long selmask[4] = {0ull, 0ull, 0ull, 0ull};
        int   idx[TOP_K];
        float wts[TOP_K];
        float wsum = 0.f;
        for (int r = 0; r < TOP_K; ++r) {
            float best = -INFINITY; int bi = -1;
            for (int a = 0; a < TOPK_GROUP; ++a) {
                const int base = ag[a] * GROUP_SZ;
                for (int i = 0; i < GROUP_SZ; ++i) {
                    const int e = base + i;
                    if ((selmask[e >> 6] >> (e & 63)) & 1ull) continue;
                    const float v = sc[e] + bias_lds[e];
                    if (v > best) { best = v; bi = e; }
                }
            }
            selmask[bi >> 6] |= 1ull << (bi & 63);
            idx[r] = bi;
            const float s = sc[bi];   // UNBIASED score for the weight
            wts[r] = s;
            wsum  += s;
        }
        const float scale = 2.5f / wsum;
        const int t_glob = t0 + tid;
        float* out_idx = out;
        float* out_wt  = out + (size_t)T_TOTAL * TOP_K;
        #pragma unroll
        for (int r = 0; r < TOP_K; ++r) {
            out_idx[t_glob * TOP_K + r] = (float)idx[r];
            out_wt [t_glob * TOP_K + r] = wts[r] * scale;
        }
    }
}

extern "C" void kernel_launch(void* const* d_in, const int* in_sizes, int n_in,
                              void* d_out, int out_size, void* d_ws, size_t ws_size,
                              hipStream_t stream) {
    const float* x    = (const float*)d_in[0];
    const float* w    = (const float*)d_in[1];
    const float* bias = (const float*)d_in[2];
    float* out = (float*)d_out;

    f16*   wf     = (f16*)d_ws;
    float* scores = (float*)((char*)d_ws + SCORES_OFF);   // 33.6 MB partials

    hipLaunchKernelGGL(pack_w_kernel, dim3((H / 32) * 16), dim3(64), 0, stream, w, wf);
    hipLaunchKernelGGL(gemm_kernel, dim3((T_TOTAL / MT) * KSPLIT), dim3(512), 0, stream,
                       x, wf, scores);
    hipLaunchKernelGGL(gate_kernel, dim3(T_TOTAL / 16), dim3(256), 0, stream,
                       scores, bias, out);
}

// Round 5
// 368.694 us; speedup vs baseline: 1.5945x; 1.5945x over previous
//
#include <hip/hip_runtime.h>
#include <math.h>

typedef __attribute__((ext_vector_type(4))) float f32x4;
typedef _Float16 f16;
typedef __attribute__((ext_vector_type(8))) _Float16 f16x8;

// Problem constants (DeepSeek-V3 gate: hidden (4,2048,7168), 256 experts)
constexpr int H       = 7168;
constexpr int E       = 256;
constexpr int T_TOTAL = 8192;     // 4*2048 tokens

constexpr int KSPLIT  = 4;
constexpr int K_SLICE = H / KSPLIT;    // 1792
constexpr int NCH     = K_SLICE / 64;  // 28 chunks of BK=64 per block
constexpr int MT      = 64;            // tokens per GEMM block (4 mtiles)

constexpr int N_GROUP    = 8;
constexpr int TOPK_GROUP = 4;
constexpr int TOP_K      = 8;

constexpr size_t SCORES_OFF = 8u * 1024 * 1024;   // ws: wf at 0 (7.34MB), scores at 8MB

// ---------------------------------------------------------------------------
// Kernel 1: split w (fp32) into f16 hi/lo in MFMA B-fragment order:
//   wf[((kc*16 + ntile)*2 + s)*512 + lane*8 + j]
//   kc = h>>5, ntile = e>>4, s = 0(hi)/1(lo), lane = ((h>>3)&3)<<4 | (e&15)
// ---------------------------------------------------------------------------
__global__ __launch_bounds__(64) void pack_w_kernel(const float* __restrict__ w,
                                                    f16* __restrict__ wf)
{
    const int l  = threadIdx.x;
    const int nt = blockIdx.x & 15;
    const int kc = blockIdx.x >> 4;
    const int e  = nt * 16 + (l & 15);
    const int h  = kc * 32 + (l >> 4) * 8;
    const float* src = &w[(size_t)e * H + h];
    f32x4 v0 = *reinterpret_cast<const f32x4*>(src);
    f32x4 v1 = *reinterpret_cast<const f32x4*>(src + 4);
    float v[8] = {v0[0], v0[1], v0[2], v0[3], v1[0], v1[1], v1[2], v1[3]};
    f16x8 hi, lo;
    #pragma unroll
    for (int j = 0; j < 8; ++j) {
        f16 h16 = (f16)v[j];
        hi[j] = h16;
        lo[j] = (f16)(v[j] - (float)h16);
    }
    const size_t base = (((size_t)kc * 16 + nt) * 2) * 512 + (size_t)l * 8;
    *reinterpret_cast<f16x8*>(&wf[base])       = hi;
    *reinterpret_cast<f16x8*>(&wf[base + 512]) = lo;
}

// ---------------------------------------------------------------------------
// Kernel 2: router GEMM, f16-split MFMA (acc += Ahi*Bhi + Ahi*Blo + Alo*Bhi).
// Grid: 512 = 64 M-tiles x 4 K-slices (2 blocks/CU); ksl = bid&3 pins one
// 1.84MB wf slice per XCD (bid%8 round-robin) -> L2-resident weights.
// Block: 512 thr = 8 waves. Block tile 64m x 256n; wave tile 64m x 32n
// (4 mtiles x 2 ntiles): 4 B-frag loads feed 24 MFMAs; B is register
// double-buffered (next K-step's loads issued before this step's MFMAs).
// No cross-wave B redundancy (each wave owns a unique 32-expert slice).
// A staged hi/lo in LDS in MFMA fragment order (lane*16B, conflict-free).
// ---------------------------------------------------------------------------
__global__ __launch_bounds__(512, 4) void gemm_kernel(
    const float* __restrict__ x,      // [T_TOTAL, H] fp32
    const f16*   __restrict__ wf,     // packed B-fragments
    float* __restrict__ scores)       // [T_TOTAL][KSPLIT][E] partial logits
{
    // [buf][mtile 0..3][ks 0..1][s 0..1][lane 0..63][j 0..7] f16 = 2 x 16 KB
    __shared__ __align__(16) f16 x_lds[2][4 * 2 * 2 * 512];

    const int tid  = threadIdx.x;
    const int lane = tid & 63;
    const int wn   = tid >> 6;     // wave 0..7: experts wn*32 .. +31

    const int bid = blockIdx.x;
    const int ksl = bid & 3;
    const int mb  = bid >> 2;      // 0..63
    const int t0  = mb * MT;
    const int k0  = ksl * K_SLICE;
    const int kc0 = k0 >> 5;       // first K-chunk-of-32 index

    // x loader: tid -> (mtile, ks, lane); 8 floats per thread per chunk
    const int lmt = (tid >> 6) & 3;
    const int lks = tid >> 8;                 // 0..1
    const float* xrow = &x[(size_t)(t0 + lmt * 16 + (lane & 15)) * H
                           + k0 + lks * 32 + (lane >> 4) * 8];

    const int lm = lane & 15;
    const int kq = lane >> 4;

    f32x4 acc[4][2];
    #pragma unroll
    for (int mt = 0; mt < 4; ++mt)
        #pragma unroll
        for (int nt = 0; nt < 2; ++nt)
            acc[mt][nt] = (f32x4){0.f, 0.f, 0.f, 0.f};

    // stage this thread's 8 floats as hi/lo fragments into LDS
    auto stage = [&](int buf, f32x4 v0, f32x4 v1) {
        float v[8] = {v0[0], v0[1], v0[2], v0[3], v1[0], v1[1], v1[2], v1[3]};
        f16x8 hi, lo;
        #pragma unroll
        for (int j = 0; j < 8; ++j) {
            f16 h16 = (f16)v[j];
            hi[j] = h16;
            lo[j] = (f16)(v[j] - (float)h16);
        }
        f16* base = &x_lds[buf][((lmt * 2 + lks) * 2) * 512 + lane * 8];
        *reinterpret_cast<f16x8*>(base)       = hi;
        *reinterpret_cast<f16x8*>(base + 512) = lo;
    };

    auto load_b = [&](f16x8 (&b)[2][2], int kc) {
        #pragma unroll
        for (int nt = 0; nt < 2; ++nt)
            #pragma unroll
            for (int s = 0; s < 2; ++s)
                b[nt][s] = *reinterpret_cast<const f16x8*>(
                    &wf[(((size_t)kc * 16 + wn * 2 + nt) * 2 + s) * 512 + lane * 8]);
    };

    auto mfma_step = [&](const f16x8 (&b)[2][2], int buf, int ks) {
        f16x8 a[4][2];
        #pragma unroll
        for (int mt = 0; mt < 4; ++mt)
            #pragma unroll
            for (int s = 0; s < 2; ++s)
                a[mt][s] = *reinterpret_cast<const f16x8*>(
                    &x_lds[buf][((mt * 2 + ks) * 2 + s) * 512 + lane * 8]);
        #pragma unroll
        for (int mt = 0; mt < 4; ++mt)              // hi*hi
            #pragma unroll
            for (int nt = 0; nt < 2; ++nt)
                acc[mt][nt] = __builtin_amdgcn_mfma_f32_16x16x32_f16(
                    a[mt][0], b[nt][0], acc[mt][nt], 0, 0, 0);
        #pragma unroll
        for (int mt = 0; mt < 4; ++mt)              // hi*lo
            #pragma unroll
            for (int nt = 0; nt < 2; ++nt)
                acc[mt][nt] = __builtin_amdgcn_mfma_f32_16x16x32_f16(
                    a[mt][0], b[nt][1], acc[mt][nt], 0, 0, 0);
        #pragma unroll
        for (int mt = 0; mt < 4; ++mt)              // lo*hi
            #pragma unroll
            for (int nt = 0; nt < 2; ++nt)
                acc[mt][nt] = __builtin_amdgcn_mfma_f32_16x16x32_f16(
                    a[mt][1], b[nt][0], acc[mt][nt], 0, 0, 0);
    };

    f16x8 b0[2][2], b1[2][2];

    // prologue: stage x chunk 0; preload first B step
    {
        f32x4 v0 = *reinterpret_cast<const f32x4*>(xrow);
        f32x4 v1 = *reinterpret_cast<const f32x4*>(xrow + 4);
        stage(0, v0, v1);
    }
    load_b(b0, kc0);
    __syncthreads();

    for (int ch = 0; ch < NCH; ++ch) {
        const int buf = ch & 1;
        // prefetch next x chunk into registers (HBM latency over this chunk)
        f32x4 nv0, nv1;
        if (ch + 1 < NCH) {
            const float* nx = xrow + (ch + 1) * 64;
            nv0 = *reinterpret_cast<const f32x4*>(nx);
            nv1 = *reinterpret_cast<const f32x4*>(nx + 4);
        }
        // B pipeline: issue next step's loads, then MFMA current step
        load_b(b1, kc0 + ch * 2 + 1);
        mfma_step(b0, buf, 0);
        load_b(b0, (ch + 1 < NCH) ? (kc0 + (ch + 1) * 2) : kc0);
        mfma_step(b1, buf, 1);

        if (ch + 1 < NCH) stage(buf ^ 1, nv0, nv1);
        __syncthreads();
    }

    // epilogue: raw partial logits, layout [T][KSPLIT][E]
    // C/D: col(expert)=lane&15, row(token)=(lane>>4)*4+reg
    #pragma unroll
    for (int mt = 0; mt < 4; ++mt)
        #pragma unroll
        for (int nt = 0; nt < 2; ++nt)
            #pragma unroll
            for (int r = 0; r < 4; ++r) {
                const int tok = mt * 16 + kq * 4 + r;
                const int e   = wn * 32 + nt * 16 + lm;
                scores[(((size_t)(t0 + tok)) * KSPLIT + ksl) * E + e] = acc[mt][nt][r];
            }
}

// ---------------------------------------------------------------------------
// Kernel 3: reduce K-split partials, sigmoid, grouped top-k gating.
// ONE TOKEN PER WAVE, fully register-resident (no LDS, no scratch arrays):
// lane l owns experts 4l..4l+3; group top-2 via 3-step shuffle merge inside
// 8-lane groups; top-4 groups via rank count; top-8 experts via 8 unrolled
// wave-argmax butterflies with lowest-index tie-break (matches lax.top_k).
// ---------------------------------------------------------------------------
__global__ __launch_bounds__(256) void gate_kernel(
    const float* __restrict__ scores,  // [T_TOTAL][KSPLIT][E]
    const float* __restrict__ bias,    // [E]
    float* __restrict__ out)           // [T*8 idx floats][T*8 weight floats]
{
    const int lane = threadIdx.x & 63;
    const int wv   = threadIdx.x >> 6;            // 0..3
    const int t    = blockIdx.x * 4 + wv;

    // reduce K-split partials: lane l covers experts 4l..4l+3
    const float* p = &scores[(size_t)t * (KSPLIT * E) + lane * 4];
    f32x4 s = (f32x4){0.f, 0.f, 0.f, 0.f};
    #pragma unroll
    for (int k = 0; k < KSPLIT; ++k)
        s += *reinterpret_cast<const f32x4*>(p + k * E);
    f32x4 bi = *reinterpret_cast<const f32x4*>(&bias[lane * 4]);

    float sig[4], bsc[4];
    #pragma unroll
    for (int j = 0; j < 4; ++j) {
        sig[j] = 1.0f / (1.0f + expf(-s[j]));
        bsc[j] = sig[j] + bi[j];
    }

    // ---- group score = sum of top-2 biased scores (group = 8 lanes) ----
    float h01 = fmaxf(bsc[0], bsc[1]), l01 = fminf(bsc[0], bsc[1]);
    float h23 = fmaxf(bsc[2], bsc[3]), l23 = fminf(bsc[2], bsc[3]);
    float m1 = fmaxf(h01, h23);
    float m2 = fmaxf(fminf(h01, h23), fmaxf(l01, l23));
    #pragma unroll
    for (int d = 1; d < 8; d <<= 1) {
        float om1 = __shfl_xor(m1, d);
        float om2 = __shfl_xor(m2, d);
        float nm1 = fmaxf(m1, om1);
        float nm2 = fmaxf(fminf(m1, om1), fmaxf(m2, om2));
        m1 = nm1; m2 = nm2;
    }
    const float gs  = m1 + m2;
    const int   gid = lane >> 3;

    // ---- top-4 groups by rank count (ties -> lowest group index) ----
    int cnt = 0;
    #pragma unroll
    for (int j = 0; j < N_GROUP; ++j) {
        float gsj = __shfl(gs, j * 8);
        cnt += (gsj > gs || (gsj == gs && j < gid)) ? 1 : 0;
    }
    const bool sel = (cnt < TOPK_GROUP);

    float mb[4];
    #pragma unroll
    for (int j = 0; j < 4; ++j) mb[j] = sel ? bsc[j] : -INFINITY;

    // ---- top-8 experts: 8 wave-argmax rounds, all-register ----
    float wsum = 0.f;
    f32x4 iv0, iv1, wv0, wv1;
    #pragma unroll
    for (int r = 0; r < TOP_K; ++r) {
        float v = mb[0]; int li = 0;
        if (mb[1] > v) { v = mb[1]; li = 1; }
        if (mb[2] > v) { v = mb[2]; li = 2; }
        if (mb[3] > v) { v = mb[3]; li = 3; }
        int ei = lane * 4 + li;
        #pragma unroll
        for (int d = 1; d < 64; d <<= 1) {
            float ov = __shfl_xor(v, d);
            int   oi = __shfl_xor(ei, d);
            if (ov > v || (ov == v && oi < ei)) { v = ov; ei = oi; }
        }
        // ei now uniform = argmax with lowest-index tie-break
        const int sub = ei & 3, owner = ei >> 2;
        const float svl = (sub & 2) ? ((sub & 1) ? sig[3] : sig[2])
                                    : ((sub & 1) ? sig[1] : sig[0]);
        const float wr = __shfl(svl, owner);      // UNBIASED score
        #pragma unroll
        for (int j = 0; j < 4; ++j)               // mask winner (static idx)
            if (lane == owner && j == sub) mb[j] = -INFINITY;
        wsum += wr;
        if (r < 4) { iv0[r] = (float)ei;     wv0[r] = wr; }
        else       { iv1[r - 4] = (float)ei; wv1[r - 4] = wr; }
    }

    const float scale = 2.5f / wsum;
    #pragma unroll
    for (int j = 0; j < 4; ++j) { wv0[j] *= scale; wv1[j] *= scale; }

    if (lane == 0) {
        float* oi_ = out + (size_t)t * TOP_K;
        float* ow_ = out + (size_t)T_TOTAL * TOP_K + (size_t)t * TOP_K;
        *reinterpret_cast<f32x4*>(oi_)     = iv0;
        *reinterpret_cast<f32x4*>(oi_ + 4) = iv1;
        *reinterpret_cast<f32x4*>(ow_)     = wv0;
        *reinterpret_cast<f32x4*>(ow_ + 4) = wv1;
    }
}

extern "C" void kernel_launch(void* const* d_in, const int* in_sizes, int n_in,
                              void* d_out, int out_size, void* d_ws, size_t ws_size,
                              hipStream_t stream) {
    const float* x    = (const float*)d_in[0];
    const float* w    = (const float*)d_in[1];
    const float* bias = (const float*)d_in[2];
    float* out = (float*)d_out;

    f16*   wf     = (f16*)d_ws;
    float* scores = (float*)((char*)d_ws + SCORES_OFF);   // 33.6 MB partials

    hipLaunchKernelGGL(pack_w_kernel, dim3((H / 32) * 16), dim3(64), 0, stream, w, wf);
    hipLaunchKernelGGL(gemm_kernel, dim3((T_TOTAL / MT) * KSPLIT), dim3(512), 0, stream,
                       x, wf, scores);
    hipLaunchKernelGGL(gate_kernel, dim3(T_TOTAL / 4), dim3(256), 0, stream,
                       scores, bias, out);
}